// Round 7
// baseline (1023.471 us; speedup 1.0000x reference)
//
#include <hip/hip_runtime.h>
#include <hip/hip_bf16.h>
#include <math.h>

typedef __hip_bfloat16 bf16;
typedef __attribute__((ext_vector_type(8))) short v8s;
typedef __attribute__((ext_vector_type(4))) float v4f;

#define EPI_F32    0
#define EPI_BF16   1
#define EPI_GELU   2
#define EPI_RESID  3
#define EPI_RESID0 4
#define EPI_WZ     5   // out_bf16 = beta*acc + enc_base[(r%896)*1024+col]
#define EPI_ATOM   6   // atomicAdd(C_f32, acc + (bias?bias[col]:0))

// ---------- bf16 helpers ----------
__device__ __forceinline__ float bf_lo(unsigned int w) { return __uint_as_float(w << 16); }
__device__ __forceinline__ float bf_hi(unsigned int w) { return __uint_as_float(w & 0xffff0000u); }
__device__ __forceinline__ unsigned short f2b_bits(float f) {
  unsigned int u = __float_as_uint(f);
  unsigned int r = (u + 0x7fffu + ((u >> 16) & 1u)) >> 16;   // RTNE
  return (unsigned short)r;
}
__device__ __forceinline__ void unpack8(uint4 u, float* f) {
  unsigned int w0 = u.x, w1 = u.y, w2 = u.z, w3 = u.w;
  f[0] = bf_lo(w0); f[1] = bf_hi(w0);
  f[2] = bf_lo(w1); f[3] = bf_hi(w1);
  f[4] = bf_lo(w2); f[5] = bf_hi(w2);
  f[6] = bf_lo(w3); f[7] = bf_hi(w3);
}
__device__ __forceinline__ void load8(const float* p, float* f) {
  float4 a = ((const float4*)p)[0];
  float4 b = ((const float4*)p)[1];
  f[0] = a.x; f[1] = a.y; f[2] = a.z; f[3] = a.w;
  f[4] = b.x; f[5] = b.y; f[6] = b.z; f[7] = b.w;
}
__device__ __forceinline__ void gl_lds16(const void* g, void* l) {
  __builtin_amdgcn_global_load_lds(
      (__attribute__((address_space(1))) void*)g,
      (__attribute__((address_space(3))) void*)l, 16, 0, 0);
}

// ---------- conversion kernels ----------
__global__ __launch_bounds__(256) void cvt_kernel(const float* __restrict__ src,
                                                  bf16* __restrict__ dst, int n)
{
  int i = (blockIdx.x * 256 + threadIdx.x) * 8;
  if (i >= n) return;
  float f[8]; load8(src + i, f);
  unsigned short us[8];
#pragma unroll
  for (int j = 0; j < 8; j++) us[j] = f2b_bits(f[j]);
  *(uint4*)((unsigned short*)dst + i) = *(uint4*)us;
}

__global__ __launch_bounds__(256) void cvt_t_kernel(const float* __restrict__ src,
                                                    bf16* __restrict__ dst, int R, int C)
{
  __shared__ float tile[32][33];
  const int c0 = blockIdx.x * 32, r0 = blockIdx.y * 32;
  const size_t bo = (size_t)blockIdx.z * R * C;
  const int tx = threadIdx.x & 31, ty = threadIdx.x >> 5;
#pragma unroll
  for (int i = 0; i < 4; i++) {
    int r = ty * 4 + i;
    tile[r][tx] = src[bo + (size_t)(r0 + r) * C + c0 + tx];
  }
  __syncthreads();
#pragma unroll
  for (int i = 0; i < 4; i++) {
    int r = ty * 4 + i;
    *((unsigned short*)dst + bo + (size_t)(c0 + r) * R + r0 + tx) = f2b_bits(tile[tx][r]);
  }
}

__global__ __launch_bounds__(256) void vt_kernel(const bf16* __restrict__ v,
                                                 bf16* __restrict__ vt)
{
  __shared__ float tile[64][65];
  const int h = blockIdx.z;
  const int t0 = blockIdx.x * 64, d0 = blockIdx.y * 64;
  const bf16* src = v + (size_t)h * 4096 * 128;
  bf16* dst = vt + (size_t)h * 128 * 4096;
  const int tid = threadIdx.x;
#pragma unroll
  for (int tt = 0; tt < 2; tt++) {
    int s = tt * 256 + tid;
    int r = s >> 3, c0 = (s & 7) * 8;
    float f[8];
    uint4 u = *(const uint4*)(src + (size_t)(t0 + r) * 128 + d0 + c0);
    unpack8(u, f);
#pragma unroll
    for (int j = 0; j < 8; j++) tile[r][c0 + j] = f[j];
  }
  __syncthreads();
#pragma unroll
  for (int tt = 0; tt < 2; tt++) {
    int s = tt * 256 + tid;
    int dr = s >> 3, c0 = (s & 7) * 8;
    unsigned short us[8];
#pragma unroll
    for (int j = 0; j < 8; j++) us[j] = f2b_bits(tile[c0 + j][dr]);
    *(uint4*)((unsigned short*)dst + (size_t)(d0 + dr) * 4096 + t0 + c0) = *(uint4*)us;
  }
}

// ---------- MFMA GEMM core, async-staged ----------
__device__ __forceinline__ void stage_async(const bf16* __restrict__ src, int ld, int r0, int k0,
                                            bf16* lds, int wave, int lane)
{
#pragma unroll
  for (int t = 0; t < 2; t++) {
    int seg = wave * 2 + t;
    const bf16* g = src + (size_t)(r0 + seg * 16 + (lane >> 2)) * ld + k0 + (lane & 3) * 8;
    gl_lds16(g, lds + seg * 512);
  }
}
__device__ __forceinline__ void stage_sync(const float* __restrict__ src, int ld, int r0, int k0,
                                           bf16* lds, int tid)
{
#pragma unroll
  for (int t = 0; t < 2; t++) {
    int s = t * 256 + tid;
    int m = s >> 2, c = s & 3;
    float f[8]; load8(src + (size_t)(r0 + m) * ld + k0 + c * 8, f);
    unsigned short us[8];
#pragma unroll
    for (int j = 0; j < 8; j++) us[j] = f2b_bits(f[j]);
    *(uint4*)&lds[m * 32 + c * 8] = *(uint4*)us;
  }
}
__device__ __forceinline__ void stage_tile(const bf16* __restrict__ src, int ld, int r0, int k0,
                                           bf16* lds, int tid, int wave, int lane)
{ stage_async(src, ld, r0, k0, lds, wave, lane); }
__device__ __forceinline__ void stage_tile(const float* __restrict__ src, int ld, int r0, int k0,
                                           bf16* lds, int tid, int wave, int lane)
{ stage_sync(src, ld, r0, k0, lds, tid); }

template<typename TA, typename TB, int EPI>
__device__ void mfma_core(const TA* __restrict__ A, int lda,
                          const TB* __restrict__ B, int ldb,
                          void* __restrict__ C, int ldc,
                          const float* __restrict__ bias,
                          const float* __restrict__ beta_p,
                          int m0, int n0, int K)
{
  __shared__ bf16 As[128 * 32];
  __shared__ bf16 Bs[128 * 32];
  const int tid = threadIdx.x;
  const int lane = tid & 63, wave = tid >> 6;
  const int mw = (wave & 1) * 64, nw = (wave >> 1) * 64;
  const int row = lane & 15, kc = lane >> 4;

  v4f acc[4][4];
  const v4f vzero = {0.f, 0.f, 0.f, 0.f};
#pragma unroll
  for (int i = 0; i < 4; i++)
#pragma unroll
    for (int j = 0; j < 4; j++) acc[i][j] = vzero;

  for (int k0 = 0; k0 < K; k0 += 32) {
    stage_tile(A, lda, m0, k0, As, tid, wave, lane);
    stage_tile(B, ldb, n0, k0, Bs, tid, wave, lane);
    __syncthreads();
    v8s af[4], bfr[4];
#pragma unroll
    for (int i = 0; i < 4; i++)
      af[i] = *(const v8s*)&As[(mw + i * 16 + row) * 32 + kc * 8];
#pragma unroll
    for (int j = 0; j < 4; j++)
      bfr[j] = *(const v8s*)&Bs[(nw + j * 16 + row) * 32 + kc * 8];
#pragma unroll
    for (int i = 0; i < 4; i++)
#pragma unroll
      for (int j = 0; j < 4; j++)
        acc[i][j] = __builtin_amdgcn_mfma_f32_16x16x32_bf16(af[i], bfr[j], acc[i][j], 0, 0, 0);
    __syncthreads();
  }

  const int cl = lane & 15, rq = lane >> 4;
  const float beta = (EPI == EPI_WZ) ? beta_p[0] : 0.f;
#pragma unroll
  for (int mi = 0; mi < 4; mi++) {
#pragma unroll
    for (int nj = 0; nj < 4; nj++) {
      const int col = n0 + nw + nj * 16 + cl;
#pragma unroll
      for (int i = 0; i < 4; i++) {
        const int r = m0 + mw + mi * 16 + rq * 4 + i;
        float v = acc[mi][nj][i];
        if (EPI == EPI_F32) {
          ((float*)C)[(size_t)r * ldc + col] = v;
        } else if (EPI == EPI_BF16) {
          ((unsigned short*)C)[(size_t)r * ldc + col] = f2b_bits(v);
        } else if (EPI == EPI_GELU) {
          v += bias[col];
          v = 0.5f * v * (1.f + erff(v * 0.70710678118654752f));
          ((unsigned short*)C)[(size_t)r * ldc + col] = f2b_bits(v);
        } else if (EPI == EPI_RESID) {
          float* Z = (float*)C;
          size_t idx = (size_t)r * ldc + col;
          Z[idx] = Z[idx] + v + bias[col];
        } else if (EPI == EPI_RESID0) {
          float* Z = (float*)C;
          size_t idx = (size_t)r * ldc + col;
          Z[idx] = Z[idx] + v;
        } else if (EPI == EPI_WZ) {
          float o = beta * v + bias[(size_t)(r % 896) * 1024 + col];
          ((unsigned short*)C)[(size_t)r * ldc + col] = f2b_bits(o);
        } else if (EPI == EPI_ATOM) {
          float add = v + (bias ? bias[col] : 0.f);
          atomicAdd(&((float*)C)[(size_t)r * ldc + col], add);
        }
      }
    }
  }
}

template<typename TA, typename TB, int EPI>
__global__ __launch_bounds__(256) void mfma_gemm(const TA* __restrict__ A, int lda,
                                                 const TB* __restrict__ B, int ldb,
                                                 void* __restrict__ C, int ldc,
                                                 const float* __restrict__ bias,
                                                 const float* __restrict__ beta_p, int K)
{
  mfma_core<TA, TB, EPI>(A, lda, B, ldb, C, ldc, bias, beta_p,
                         blockIdx.y * 128, blockIdx.x * 128, K);
}

// XCD-swizzled variant for M=16384 (128 M-blocks)
template<typename TA, typename TB, int EPI>
__global__ __launch_bounds__(256) void mfma_gemm_sw(const TA* __restrict__ A, int lda,
                                                    const TB* __restrict__ B, int ldb,
                                                    void* __restrict__ C, int ldc,
                                                    const float* __restrict__ bias,
                                                    const float* __restrict__ beta_p, int K)
{
  const int lin = blockIdx.x;
  const int m0 = ((((lin & 7) << 4) | ((lin >> 3) & 15))) * 128;
  const int n0 = (lin >> 7) * 128;
  mfma_core<TA, TB, EPI>(A, lda, B, ldb, C, ldc, bias, beta_p, m0, n0, K);
}

// split-K atomic variant: grid (Nb, Mb, SK), chunk z covers K [z*Kc, (z+1)*Kc)
template<typename TA, typename TB>
__global__ __launch_bounds__(256) void mfma_gemm_sk(const TA* __restrict__ A, int lda,
                                                    const TB* __restrict__ B, int ldb,
                                                    float* __restrict__ C, int ldc,
                                                    const float* __restrict__ bias, int Kc)
{
  const int kofs = blockIdx.z * Kc;
  mfma_core<TA, TB, EPI_ATOM>(A + kofs, lda, B + kofs, ldb, C, ldc,
                              (blockIdx.z == 0) ? bias : nullptr, nullptr,
                              blockIdx.y * 128, blockIdx.x * 128, Kc);
}

// ---------- batched QKV projection ----------
__global__ __launch_bounds__(256) void qkv_mfma(const bf16* __restrict__ hin,
                                                const bf16* __restrict__ Wt,
                                                bf16* __restrict__ qkv,
                                                const int* __restrict__ tptr)
{
  const int zb = blockIdx.z;
  const int type = zb / 12, rem = zb % 12, n = rem / 3, kh = rem % 3;
  const int phase = ((tptr[0] % 4) + 4) % 4;
  const int hid = (kh == 0) ? n
                : (kh == 1) ? 4 + (n + 2 * (phase & 1)) % 4
                            : 8 + (n + phase) % 4;
  const bf16* B = Wt + ((size_t)type * 12 + hid) * 128 * 896;
  bf16* out = qkv + ((size_t)type * 12 + n * 3 + kh) * 4096 * 128;
  mfma_core<bf16, bf16, EPI_BF16>(hin + n * 896, 3584, B, 896, out, 128,
                                  nullptr, nullptr, blockIdx.y * 128, 0, 896);
}

// ---------- LayerNorm ----------
__global__ __launch_bounds__(256) void ln_kernel(const float* __restrict__ in,
                                                 const float* __restrict__ g,
                                                 const float* __restrict__ bsh,
                                                 bf16* __restrict__ out, int D)
{
  __shared__ float row[3584];
  __shared__ float red[256];
  const int tid = threadIdx.x;
  const size_t base = (size_t)blockIdx.x * D;
  float s = 0.f;
  for (int i = tid; i < D; i += 256) { float v = in[base + i]; row[i] = v; s += v; }
  red[tid] = s; __syncthreads();
  for (int o = 128; o > 0; o >>= 1) { if (tid < o) red[tid] += red[tid + o]; __syncthreads(); }
  const float mean = red[0] / (float)D;
  __syncthreads();
  s = 0.f;
  for (int i = tid; i < D; i += 256) { float d = row[i] - mean; s += d * d; }
  red[tid] = s; __syncthreads();
  for (int o = 128; o > 0; o >>= 1) { if (tid < o) red[tid] += red[tid + o]; __syncthreads(); }
  const float inv = rsqrtf(red[0] / (float)D + 1e-5f);
  for (int i = tid; i < D; i += 256) {
    float v = (row[i] - mean) * inv * g[i] + bsh[i];
    *((unsigned short*)out + base + i) = f2b_bits(v);
  }
}

// ---------- MFMA flash attention (proven R4) ----------
__global__ __launch_bounds__(256) void attn_mfma(const bf16* __restrict__ qkv,
                                                 const bf16* __restrict__ vt,
                                                 float* __restrict__ z,
                                                 const int* __restrict__ tptr)
{
  __shared__ bf16 Ks[64 * 136];
  __shared__ bf16 Vs[128 * 72];
  __shared__ bf16 Ps[4][16 * 72];
  const int tid = threadIdx.x;
  const int lane = tid & 63, wave = tid >> 6;
  const int cl = lane & 15, rq = lane >> 4;
  const int qb = 15 - blockIdx.x;
  const int bnk = blockIdx.y;
  const int b = bnk / 12, rem = bnk % 12, n = rem / 3, kh = rem % 3;
  const int phase = ((tptr[0] % 4) + 4) % 4;
  const int slot = (kh == 0) ? 0 : (kh == 1) ? 1 + (phase & 1) : 3 + phase;
  const int head = n * 3 + kh;
  const size_t HS = (size_t)12 * 4096 * 128;
  const bf16* qp = qkv + ((size_t)head * 4096 + b * 1024) * 128;
  const bf16* kp = qkv + HS + ((size_t)head * 4096 + b * 1024) * 128;
  const bf16* vtp = vt + (size_t)head * 128 * 4096;

  v8s aq[4];
  {
    const bf16* qrow = qp + (size_t)(qb * 64 + wave * 16 + cl) * 128 + rq * 8;
#pragma unroll
    for (int c = 0; c < 4; c++) aq[c] = *(const v8s*)(qrow + c * 32);
  }
  v4f oacc[8];
  const v4f vzero = {0.f, 0.f, 0.f, 0.f};
#pragma unroll
  for (int c = 0; c < 8; c++) oacc[c] = vzero;
  float m_i[4] = {-1e30f, -1e30f, -1e30f, -1e30f};
  float l_i[4] = {0.f, 0.f, 0.f, 0.f};

  for (int kt = 0; kt <= qb; kt++) {
    __syncthreads();
#pragma unroll
    for (int t = 0; t < 4; t++) {
      int s = t * 256 + tid;
      int r = s >> 4, c0 = (s & 15) * 8;
      *(uint4*)&Ks[r * 136 + c0] = *(const uint4*)(kp + (size_t)(kt * 64 + r) * 128 + c0);
    }
#pragma unroll
    for (int t = 0; t < 4; t++) {
      int s = t * 256 + tid;
      int d = s >> 3, c0 = (s & 7) * 8;
      *(uint4*)&Vs[d * 72 + c0] =
          *(const uint4*)(vtp + (size_t)d * 4096 + b * 1024 + kt * 64 + c0);
    }
    __syncthreads();

    v4f s_acc[4];
#pragma unroll
    for (int blk = 0; blk < 4; blk++) {
      s_acc[blk] = vzero;
#pragma unroll
      for (int c = 0; c < 4; c++) {
        v8s bk = *(const v8s*)&Ks[(blk * 16 + cl) * 136 + c * 32 + rq * 8];
        s_acc[blk] = __builtin_amdgcn_mfma_f32_16x16x32_bf16(aq[c], bk, s_acc[blk], 0, 0, 0);
      }
    }
#pragma unroll
    for (int blk = 0; blk < 4; blk++)
#pragma unroll
      for (int i = 0; i < 4; i++) {
        float sv = s_acc[blk][i] * 0.088388347648318447f;
        if (kt == qb && (blk * 16 + cl) > (wave * 16 + rq * 4 + i)) sv = -1e30f;
        s_acc[blk][i] = sv;
      }
    float al[4];
#pragma unroll
    for (int i = 0; i < 4; i++) {
      float mx = fmaxf(fmaxf(s_acc[0][i], s_acc[1][i]), fmaxf(s_acc[2][i], s_acc[3][i]));
      mx = fmaxf(mx, __shfl_xor(mx, 1, 64));
      mx = fmaxf(mx, __shfl_xor(mx, 2, 64));
      mx = fmaxf(mx, __shfl_xor(mx, 4, 64));
      mx = fmaxf(mx, __shfl_xor(mx, 8, 64));
      const float mn = fmaxf(m_i[i], mx);
      al[i] = __expf(m_i[i] - mn);
      m_i[i] = mn;
      float ps = 0.f;
#pragma unroll
      for (int blk = 0; blk < 4; blk++) {
        float p = __expf(s_acc[blk][i] - mn);
        s_acc[blk][i] = p;
        ps += p;
      }
      ps += __shfl_xor(ps, 1, 64);
      ps += __shfl_xor(ps, 2, 64);
      ps += __shfl_xor(ps, 4, 64);
      ps += __shfl_xor(ps, 8, 64);
      l_i[i] = l_i[i] * al[i] + ps;
    }
#pragma unroll
    for (int c = 0; c < 8; c++)
#pragma unroll
      for (int i = 0; i < 4; i++) oacc[c][i] *= al[i];
    bf16* ps = Ps[wave];
#pragma unroll
    for (int blk = 0; blk < 4; blk++)
#pragma unroll
      for (int i = 0; i < 4; i++)
        *((unsigned short*)ps + (rq * 4 + i) * 72 + blk * 16 + cl) = f2b_bits(s_acc[blk][i]);
    v8s pa[2];
#pragma unroll
    for (int c = 0; c < 2; c++)
      pa[c] = *(const v8s*)&ps[cl * 72 + c * 32 + rq * 8];
#pragma unroll
    for (int c = 0; c < 8; c++)
#pragma unroll
      for (int ch = 0; ch < 2; ch++) {
        v8s bv = *(const v8s*)&Vs[(c * 16 + cl) * 72 + ch * 32 + rq * 8];
        oacc[c] = __builtin_amdgcn_mfma_f32_16x16x32_bf16(pa[ch], bv, oacc[c], 0, 0, 0);
      }
  }
#pragma unroll
  for (int c = 0; c < 8; c++) {
    const int d = c * 16 + cl;
#pragma unroll
    for (int i = 0; i < 4; i++) {
      const int t = qb * 64 + wave * 16 + rq * 4 + i;
      float* dst = z + ((size_t)(b * 1024 + t)) * 3584 + n * 896 + slot * 128 + d;
      *dst += oacc[c][i] / l_i[i];
    }
  }
}

// ---------------------------------------------------------------------------
extern "C" void kernel_launch(void* const* d_in, const int* in_sizes, int n_in,
                              void* d_out, int out_size, void* d_ws, size_t ws_size,
                              hipStream_t stream)
{
  const float* x        = (const float*)d_in[0];
  const int*   tptr     = (const int*)d_in[1];
  const float* enc_base = (const float*)d_in[2];
  const float* enc_A    = (const float*)d_in[3];
  const float* enc_B    = (const float*)d_in[4];
  const float* beta_p   = (const float*)d_in[5];
  const float* lnm_g    = (const float*)d_in[6];
  const float* lnm_b    = (const float*)d_in[7];
  const float* w1       = (const float*)d_in[8];
  const float* b1       = (const float*)d_in[9];
  const float* w2       = (const float*)d_in[10];
  const float* b2       = (const float*)d_in[11];
  const float* lna_g    = (const float*)d_in[12];
  const float* lna_b    = (const float*)d_in[13];
  const float* Wq       = (const float*)d_in[14];
  const float* Wk       = (const float*)d_in[15];
  const float* Wv       = (const float*)d_in[16];
  const float* dln_g    = (const float*)d_in[17];
  const float* dln_b    = (const float*)d_in[18];
  const float* down_w   = (const float*)d_in[19];
  const float* up_w     = (const float*)d_in[20];

  const bool big = (ws_size >= (size_t)228458496);
  char* ws = (char*)d_ws;
  float* z = (float*)ws;
  char* ra = ws + (size_t)58720256;           // regionA (>=37.7MB both paths)
  bf16 *act, *qkv, *bufb, *w1b, *w2b, *encBt, *Wt;
  if (big) {
    act   = (bf16*)ra;
    qkv   = (bf16*)ra;
    bufb  = (bf16*)(ws + (size_t)176160768);
    w1b   = (bf16*)(ws + (size_t)205520896);
    w2b   = (bf16*)(ws + (size_t)211943424);
    encBt = (bf16*)(ws + (size_t)218365952);
    Wt    = (bf16*)(ws + (size_t)220200960);
  } else {
    act   = (bf16*)ra;
    qkv   = (bf16*)ra;
    bufb  = (bf16*)(ws + (size_t)96468992);
    w1b   = (bf16*)(ws + (size_t)125829120);
    w2b   = (bf16*)(ws + (size_t)132251648);
    encBt = (bf16*)(ws + (size_t)138674176);
    Wt    = (bf16*)(ws + (size_t)140509184);
  }
  // encoder-phase scratch in regionA (dead before mixer writes act):
  bf16* xb    = (bf16*)ra;                        // 4096x1024 bf16 (8.4MB)
  bf16* encAt = (bf16*)(ra + (size_t)8912896);    // 1024x256 (0.5MB)
  bf16* Wz    = (bf16*)(ra + (size_t)9437184);    // 3584x1024 (7.3MB)
  // decoder-phase scratch in regionA (qkv dead after attention):
  bf16* dwT   = (bf16*)ra;                        // 3584x256 (1.8MB)
  bf16* Wdec  = (bf16*)(ra + (size_t)2097152);    // 1024x3584 (7.3MB)

  dim3 blk(256);
  hipMemsetAsync(d_out, 0, (size_t)4096 * 1024 * 4, stream);

  // --- weight conversion / precompute ---
  cvt_kernel<<<1568, blk, 0, stream>>>(w1, w1b, 3211264);
  cvt_kernel<<<1568, blk, 0, stream>>>(w2, w2b, 3211264);
  cvt_kernel<<<2048, blk, 0, stream>>>(x, xb, 4194304);
  cvt_t_kernel<<<dim3(112, 8, 1), blk, 0, stream>>>(enc_B, encBt, 256, 3584);
  cvt_t_kernel<<<dim3(32, 8, 1), blk, 0, stream>>>(enc_A, encAt, 256, 1024);
  cvt_t_kernel<<<dim3(4, 28, 12), blk, 0, stream>>>(Wq, Wt,                      896, 128);
  cvt_t_kernel<<<dim3(4, 28, 12), blk, 0, stream>>>(Wk, Wt + (size_t)12*128*896, 896, 128);
  cvt_t_kernel<<<dim3(4, 28, 12), blk, 0, stream>>>(Wv, Wt + (size_t)24*128*896, 896, 128);
  // Wz[nd,k] = enc_base[nd%896,k] + beta * sum_r encB[r,nd]*encA[r,k]
  mfma_gemm<bf16, bf16, EPI_WZ><<<dim3(8, 28), blk, 0, stream>>>(
      encBt, 256, encAt, 256, Wz, 1024, enc_base, beta_p, 256);

  // encoder: z = xb @ Wz^T   (4096x3584, K=1024)
  mfma_gemm<bf16, bf16, EPI_F32><<<dim3(28, 32), blk, 0, stream>>>(
      xb, 1024, Wz, 1024, z, 3584, nullptr, nullptr, 1024);

  // zm = LN(z) over 896
  ln_kernel<<<dim3(16384), blk, 0, stream>>>(z, lnm_g, lnm_b, bufb, 896);

  // mixer
  if (big) {
    mfma_gemm_sw<bf16, bf16, EPI_GELU><<<dim3(3584), blk, 0, stream>>>(bufb, 896, w1b, 896, act, 3584, b1, nullptr, 896);
    mfma_gemm_sk<bf16, bf16><<<dim3(7, 128, 2), blk, 0, stream>>>(act, 3584, w2b, 3584, z, 896, b2, 1792);
  } else {
    for (int c = 0; c < 4; c++) {
      mfma_gemm_sw<bf16, bf16, EPI_GELU><<<dim3(896), blk, 0, stream>>>(
          bufb, 896, w1b + (size_t)c * 896 * 896, 896, act, 896, b1 + c * 896, nullptr, 896);
      if (c == 0)
        mfma_gemm_sw<bf16, bf16, EPI_RESID><<<dim3(896), blk, 0, stream>>>(
            act, 896, w2b + (size_t)c * 896, 3584, z, 896, b2, nullptr, 896);
      else
        mfma_gemm_sw<bf16, bf16, EPI_RESID0><<<dim3(896), blk, 0, stream>>>(
            act, 896, w2b + (size_t)c * 896, 3584, z, 896, nullptr, nullptr, 896);
    }
  }

  // hin = LN(z) over 896
  ln_kernel<<<dim3(16384), blk, 0, stream>>>(z, lna_g, lna_b, bufb, 896);
  // q,k,v projections
  qkv_mfma<<<dim3(1, 32, 36), blk, 0, stream>>>(bufb, Wt, qkv, tptr);
  // transpose V -> V^T in bufb
  vt_kernel<<<dim3(64, 2, 12), blk, 0, stream>>>(qkv + (size_t)24 * 4096 * 128, bufb);
  // flash attention, adds into z slots
  attn_mfma<<<dim3(16, 48), blk, 0, stream>>>(qkv, bufb, z, tptr);

  // decoder precompute (qkv dead now): Wdec[i,c] = sum_r up_w[i,r]*down_w[r,c]
  cvt_t_kernel<<<dim3(112, 8, 1), blk, 0, stream>>>(down_w, dwT, 256, 3584);
  mfma_gemm<float, bf16, EPI_BF16><<<dim3(28, 8), blk, 0, stream>>>(
      up_w, 256, dwT, 256, Wdec, 3584, nullptr, nullptr, 256);

  // c = LN(z) over 3584
  ln_kernel<<<dim3(4096), blk, 0, stream>>>(z, dln_g, dln_b, bufb, 3584);
  // y = c @ Wdec^T  (4096x1024, K=3584, split-K=4, atomic into zeroed d_out)
  mfma_gemm_sk<bf16, bf16><<<dim3(8, 32, 4), blk, 0, stream>>>(
      bufb, 3584, Wdec, 3584, (float*)d_out, 1024, nullptr, 896);
}

// Round 8
// 983.421 us; speedup vs baseline: 1.0407x; 1.0407x over previous
//
#include <hip/hip_runtime.h>
#include <hip/hip_bf16.h>
#include <math.h>

typedef __hip_bfloat16 bf16;
typedef __attribute__((ext_vector_type(8))) short v8s;
typedef __attribute__((ext_vector_type(4))) float v4f;

#define EPI_F32    0
#define EPI_BF16   1
#define EPI_GELU   2
#define EPI_RESID  3
#define EPI_RESID0 4
#define EPI_WZ     5   // out_bf16 = beta*acc + enc_base[(r%896)*1024+col]
#define EPI_ATOM   6   // atomicAdd(C_f32, acc + (bias?bias[col]:0))
#define EPI_VT     7   // transposed bf16 store: C[(col)*4096 + r]

// ---------- bf16 helpers ----------
__device__ __forceinline__ float bf_lo(unsigned int w) { return __uint_as_float(w << 16); }
__device__ __forceinline__ float bf_hi(unsigned int w) { return __uint_as_float(w & 0xffff0000u); }
__device__ __forceinline__ unsigned short f2b_bits(float f) {
  unsigned int u = __float_as_uint(f);
  unsigned int r = (u + 0x7fffu + ((u >> 16) & 1u)) >> 16;   // RTNE
  return (unsigned short)r;
}
__device__ __forceinline__ void unpack8(uint4 u, float* f) {
  unsigned int w0 = u.x, w1 = u.y, w2 = u.z, w3 = u.w;
  f[0] = bf_lo(w0); f[1] = bf_hi(w0);
  f[2] = bf_lo(w1); f[3] = bf_hi(w1);
  f[4] = bf_lo(w2); f[5] = bf_hi(w2);
  f[6] = bf_lo(w3); f[7] = bf_hi(w3);
}
__device__ __forceinline__ void load8(const float* p, float* f) {
  float4 a = ((const float4*)p)[0];
  float4 b = ((const float4*)p)[1];
  f[0] = a.x; f[1] = a.y; f[2] = a.z; f[3] = a.w;
  f[4] = b.x; f[5] = b.y; f[6] = b.z; f[7] = b.w;
}
__device__ __forceinline__ void gl_lds16(const void* g, void* l) {
  __builtin_amdgcn_global_load_lds(
      (__attribute__((address_space(1))) void*)g,
      (__attribute__((address_space(3))) void*)l, 16, 0, 0);
}

// ---------- conversion kernels ----------
__global__ __launch_bounds__(256) void cvt_kernel(const float* __restrict__ src,
                                                  bf16* __restrict__ dst, int n)
{
  int i = (blockIdx.x * 256 + threadIdx.x) * 8;
  if (i >= n) return;
  float f[8]; load8(src + i, f);
  unsigned short us[8];
#pragma unroll
  for (int j = 0; j < 8; j++) us[j] = f2b_bits(f[j]);
  *(uint4*)((unsigned short*)dst + i) = *(uint4*)us;
}

__global__ __launch_bounds__(256) void cvt_t_kernel(const float* __restrict__ src,
                                                    bf16* __restrict__ dst, int R, int C)
{
  __shared__ float tile[32][33];
  const int c0 = blockIdx.x * 32, r0 = blockIdx.y * 32;
  const size_t bo = (size_t)blockIdx.z * R * C;
  const int tx = threadIdx.x & 31, ty = threadIdx.x >> 5;
#pragma unroll
  for (int i = 0; i < 4; i++) {
    int r = ty * 4 + i;
    tile[r][tx] = src[bo + (size_t)(r0 + r) * C + c0 + tx];
  }
  __syncthreads();
#pragma unroll
  for (int i = 0; i < 4; i++) {
    int r = ty * 4 + i;
    *((unsigned short*)dst + bo + (size_t)(c0 + r) * R + r0 + tx) = f2b_bits(tile[tx][r]);
  }
}

// ---------- MFMA GEMM core, async-staged ----------
__device__ __forceinline__ void stage_async(const bf16* __restrict__ src, int ld, int r0, int k0,
                                            bf16* lds, int wave, int lane)
{
#pragma unroll
  for (int t = 0; t < 2; t++) {
    int seg = wave * 2 + t;
    const bf16* g = src + (size_t)(r0 + seg * 16 + (lane >> 2)) * ld + k0 + (lane & 3) * 8;
    gl_lds16(g, lds + seg * 512);
  }
}
__device__ __forceinline__ void stage_sync(const float* __restrict__ src, int ld, int r0, int k0,
                                           bf16* lds, int tid)
{
#pragma unroll
  for (int t = 0; t < 2; t++) {
    int s = t * 256 + tid;
    int m = s >> 2, c = s & 3;
    float f[8]; load8(src + (size_t)(r0 + m) * ld + k0 + c * 8, f);
    unsigned short us[8];
#pragma unroll
    for (int j = 0; j < 8; j++) us[j] = f2b_bits(f[j]);
    *(uint4*)&lds[m * 32 + c * 8] = *(uint4*)us;
  }
}
__device__ __forceinline__ void stage_tile(const bf16* __restrict__ src, int ld, int r0, int k0,
                                           bf16* lds, int tid, int wave, int lane)
{ stage_async(src, ld, r0, k0, lds, wave, lane); }
__device__ __forceinline__ void stage_tile(const float* __restrict__ src, int ld, int r0, int k0,
                                           bf16* lds, int tid, int wave, int lane)
{ stage_sync(src, ld, r0, k0, lds, tid); }

template<typename TA, typename TB, int EPI>
__device__ void mfma_core(const TA* __restrict__ A, int lda,
                          const TB* __restrict__ B, int ldb,
                          void* __restrict__ C, int ldc,
                          const float* __restrict__ bias,
                          const float* __restrict__ beta_p,
                          int m0, int n0, int K)
{
  __shared__ bf16 As[128 * 32];
  __shared__ bf16 Bs[128 * 32];
  const int tid = threadIdx.x;
  const int lane = tid & 63, wave = tid >> 6;
  const int mw = (wave & 1) * 64, nw = (wave >> 1) * 64;
  const int row = lane & 15, kc = lane >> 4;

  v4f acc[4][4];
  const v4f vzero = {0.f, 0.f, 0.f, 0.f};
#pragma unroll
  for (int i = 0; i < 4; i++)
#pragma unroll
    for (int j = 0; j < 4; j++) acc[i][j] = vzero;

  for (int k0 = 0; k0 < K; k0 += 32) {
    stage_tile(A, lda, m0, k0, As, tid, wave, lane);
    stage_tile(B, ldb, n0, k0, Bs, tid, wave, lane);
    __syncthreads();
    v8s af[4], bfr[4];
#pragma unroll
    for (int i = 0; i < 4; i++)
      af[i] = *(const v8s*)&As[(mw + i * 16 + row) * 32 + kc * 8];
#pragma unroll
    for (int j = 0; j < 4; j++)
      bfr[j] = *(const v8s*)&Bs[(nw + j * 16 + row) * 32 + kc * 8];
#pragma unroll
    for (int i = 0; i < 4; i++)
#pragma unroll
      for (int j = 0; j < 4; j++)
        acc[i][j] = __builtin_amdgcn_mfma_f32_16x16x32_bf16(af[i], bfr[j], acc[i][j], 0, 0, 0);
    __syncthreads();
  }

  const int cl = lane & 15, rq = lane >> 4;
  if (EPI == EPI_VT) {
    // transposed store: vt[(d=col)][t=r], pack 4 consecutive t
#pragma unroll
    for (int mi = 0; mi < 4; mi++) {
#pragma unroll
      for (int nj = 0; nj < 4; nj++) {
        const int col = n0 + nw + nj * 16 + cl;
        const int rb = m0 + mw + mi * 16 + rq * 4;
        unsigned short us[4];
#pragma unroll
        for (int i = 0; i < 4; i++) us[i] = f2b_bits(acc[mi][nj][i]);
        *(ushort2*)((unsigned short*)C + (size_t)col * 4096 + rb) = *(ushort2*)us;
        *(ushort2*)((unsigned short*)C + (size_t)col * 4096 + rb + 2) = *(ushort2*)(us + 2);
      }
    }
    return;
  }
  const float beta = (EPI == EPI_WZ) ? beta_p[0] : 0.f;
#pragma unroll
  for (int mi = 0; mi < 4; mi++) {
#pragma unroll
    for (int nj = 0; nj < 4; nj++) {
      const int col = n0 + nw + nj * 16 + cl;
#pragma unroll
      for (int i = 0; i < 4; i++) {
        const int r = m0 + mw + mi * 16 + rq * 4 + i;
        float v = acc[mi][nj][i];
        if (EPI == EPI_F32) {
          ((float*)C)[(size_t)r * ldc + col] = v;
        } else if (EPI == EPI_BF16) {
          ((unsigned short*)C)[(size_t)r * ldc + col] = f2b_bits(v);
        } else if (EPI == EPI_GELU) {
          v += bias[col];
          v = 0.5f * v * (1.f + erff(v * 0.70710678118654752f));
          ((unsigned short*)C)[(size_t)r * ldc + col] = f2b_bits(v);
        } else if (EPI == EPI_RESID) {
          float* Z = (float*)C;
          size_t idx = (size_t)r * ldc + col;
          Z[idx] = Z[idx] + v + bias[col];
        } else if (EPI == EPI_RESID0) {
          float* Z = (float*)C;
          size_t idx = (size_t)r * ldc + col;
          Z[idx] = Z[idx] + v;
        } else if (EPI == EPI_WZ) {
          float o = beta * v + bias[(size_t)(r % 896) * 1024 + col];
          ((unsigned short*)C)[(size_t)r * ldc + col] = f2b_bits(o);
        } else if (EPI == EPI_ATOM) {
          float add = v + (bias ? bias[col] : 0.f);
          atomicAdd(&((float*)C)[(size_t)r * ldc + col], add);
        }
      }
    }
  }
}

template<typename TA, typename TB, int EPI>
__global__ __launch_bounds__(256) void mfma_gemm(const TA* __restrict__ A, int lda,
                                                 const TB* __restrict__ B, int ldb,
                                                 void* __restrict__ C, int ldc,
                                                 const float* __restrict__ bias,
                                                 const float* __restrict__ beta_p, int K)
{
  mfma_core<TA, TB, EPI>(A, lda, B, ldb, C, ldc, bias, beta_p,
                         blockIdx.y * 128, blockIdx.x * 128, K);
}

// XCD-swizzled variant for M=16384 (128 M-blocks)
template<typename TA, typename TB, int EPI>
__global__ __launch_bounds__(256) void mfma_gemm_sw(const TA* __restrict__ A, int lda,
                                                    const TB* __restrict__ B, int ldb,
                                                    void* __restrict__ C, int ldc,
                                                    const float* __restrict__ bias,
                                                    const float* __restrict__ beta_p, int K)
{
  const int lin = blockIdx.x;
  const int m0 = ((((lin & 7) << 4) | ((lin >> 3) & 15))) * 128;
  const int n0 = (lin >> 7) * 128;
  mfma_core<TA, TB, EPI>(A, lda, B, ldb, C, ldc, bias, beta_p, m0, n0, K);
}

// swizzled split-K=2 atomic variant for M=16384: adjacent lins share tile
// (same B/A blocks in L2), differ in K-chunk; lin>>1 uses the R6 XCD mapping.
template<typename TA, typename TB>
__global__ __launch_bounds__(256) void mfma_gemm_sk_sw(const TA* __restrict__ A, int lda,
                                                       const TB* __restrict__ B, int ldb,
                                                       float* __restrict__ C, int ldc,
                                                       const float* __restrict__ bias, int Kc)
{
  const int chunk = blockIdx.x & 1;
  const int l2 = blockIdx.x >> 1;
  const int m0 = ((((l2 & 7) << 4) | ((l2 >> 3) & 15))) * 128;
  const int n0 = (l2 >> 7) * 128;
  const int kofs = chunk * Kc;
  mfma_core<TA, TB, EPI_ATOM>(A + kofs, lda, B + kofs, ldb, C, ldc,
                              (chunk == 0) ? bias : nullptr, nullptr, m0, n0, Kc);
}

// plain split-K atomic variant: grid (Nb, Mb, SK)
template<typename TA, typename TB>
__global__ __launch_bounds__(256) void mfma_gemm_sk(const TA* __restrict__ A, int lda,
                                                    const TB* __restrict__ B, int ldb,
                                                    float* __restrict__ C, int ldc,
                                                    const float* __restrict__ bias, int Kc)
{
  const int kofs = blockIdx.z * Kc;
  mfma_core<TA, TB, EPI_ATOM>(A + kofs, lda, B + kofs, ldb, C, ldc,
                              (blockIdx.z == 0) ? bias : nullptr, nullptr,
                              blockIdx.y * 128, blockIdx.x * 128, Kc);
}

// ---------- batched QK projection (types 0,1) ----------
__global__ __launch_bounds__(256) void qkv_mfma(const bf16* __restrict__ hin,
                                                const bf16* __restrict__ Wt,
                                                bf16* __restrict__ qkv,
                                                const int* __restrict__ tptr)
{
  const int zb = blockIdx.z;
  const int type = zb / 12, rem = zb % 12, n = rem / 3, kh = rem % 3;
  const int phase = ((tptr[0] % 4) + 4) % 4;
  const int hid = (kh == 0) ? n
                : (kh == 1) ? 4 + (n + 2 * (phase & 1)) % 4
                            : 8 + (n + phase) % 4;
  const bf16* B = Wt + ((size_t)type * 12 + hid) * 128 * 896;
  bf16* out = qkv + ((size_t)type * 12 + n * 3 + kh) * 4096 * 128;
  mfma_core<bf16, bf16, EPI_BF16>(hin + n * 896, 3584, B, 896, out, 128,
                                  nullptr, nullptr, blockIdx.y * 128, 0, 896);
}

// ---------- V projection, writes V^T [head][128][4096] directly ----------
__global__ __launch_bounds__(256) void qkv_v_mfma(const bf16* __restrict__ hin,
                                                  const bf16* __restrict__ Wt,
                                                  bf16* __restrict__ vt,
                                                  const int* __restrict__ tptr)
{
  const int rem = blockIdx.z, n = rem / 3, kh = rem % 3;
  const int phase = ((tptr[0] % 4) + 4) % 4;
  const int hid = (kh == 0) ? n
                : (kh == 1) ? 4 + (n + 2 * (phase & 1)) % 4
                            : 8 + (n + phase) % 4;
  const bf16* B = Wt + ((size_t)2 * 12 + hid) * 128 * 896;
  bf16* out = vt + (size_t)(n * 3 + kh) * 128 * 4096;
  mfma_core<bf16, bf16, EPI_VT>(hin + n * 896, 3584, B, 896, out, 0,
                                nullptr, nullptr, blockIdx.y * 128, 0, 896);
}

// ---------- LayerNorm ----------
__global__ __launch_bounds__(256) void ln_kernel(const float* __restrict__ in,
                                                 const float* __restrict__ g,
                                                 const float* __restrict__ bsh,
                                                 bf16* __restrict__ out, int D)
{
  __shared__ float row[3584];
  __shared__ float red[256];
  const int tid = threadIdx.x;
  const size_t base = (size_t)blockIdx.x * D;
  float s = 0.f;
  for (int i = tid; i < D; i += 256) { float v = in[base + i]; row[i] = v; s += v; }
  red[tid] = s; __syncthreads();
  for (int o = 128; o > 0; o >>= 1) { if (tid < o) red[tid] += red[tid + o]; __syncthreads(); }
  const float mean = red[0] / (float)D;
  __syncthreads();
  s = 0.f;
  for (int i = tid; i < D; i += 256) { float d = row[i] - mean; s += d * d; }
  red[tid] = s; __syncthreads();
  for (int o = 128; o > 0; o >>= 1) { if (tid < o) red[tid] += red[tid + o]; __syncthreads(); }
  const float inv = rsqrtf(red[0] / (float)D + 1e-5f);
  for (int i = tid; i < D; i += 256) {
    float v = (row[i] - mean) * inv * g[i] + bsh[i];
    *((unsigned short*)out + base + i) = f2b_bits(v);
  }
}

// ---------- MFMA flash attention ----------
__global__ __launch_bounds__(256) void attn_mfma(const bf16* __restrict__ qkv,
                                                 const bf16* __restrict__ vt,
                                                 float* __restrict__ z,
                                                 const int* __restrict__ tptr)
{
  __shared__ bf16 Ks[64 * 136];
  __shared__ bf16 Vs[128 * 72];
  __shared__ bf16 Ps[4][16 * 72];
  const int tid = threadIdx.x;
  const int lane = tid & 63, wave = tid >> 6;
  const int cl = lane & 15, rq = lane >> 4;
  const int qb = 15 - blockIdx.x;
  const int bnk = blockIdx.y;
  const int b = bnk / 12, rem = bnk % 12, n = rem / 3, kh = rem % 3;
  const int phase = ((tptr[0] % 4) + 4) % 4;
  const int slot = (kh == 0) ? 0 : (kh == 1) ? 1 + (phase & 1) : 3 + phase;
  const int head = n * 3 + kh;
  const size_t HS = (size_t)12 * 4096 * 128;
  const bf16* qp = qkv + ((size_t)head * 4096 + b * 1024) * 128;
  const bf16* kp = qkv + HS + ((size_t)head * 4096 + b * 1024) * 128;
  const bf16* vtp = vt + (size_t)head * 128 * 4096;

  v8s aq[4];
  {
    const bf16* qrow = qp + (size_t)(qb * 64 + wave * 16 + cl) * 128 + rq * 8;
#pragma unroll
    for (int c = 0; c < 4; c++) aq[c] = *(const v8s*)(qrow + c * 32);
  }
  v4f oacc[8];
  const v4f vzero = {0.f, 0.f, 0.f, 0.f};
#pragma unroll
  for (int c = 0; c < 8; c++) oacc[c] = vzero;
  float m_i[4] = {-1e30f, -1e30f, -1e30f, -1e30f};
  float l_i[4] = {0.f, 0.f, 0.f, 0.f};

  for (int kt = 0; kt <= qb; kt++) {
    __syncthreads();
#pragma unroll
    for (int t = 0; t < 4; t++) {
      int s = t * 256 + tid;
      int r = s >> 4, c0 = (s & 15) * 8;
      *(uint4*)&Ks[r * 136 + c0] = *(const uint4*)(kp + (size_t)(kt * 64 + r) * 128 + c0);
    }
#pragma unroll
    for (int t = 0; t < 4; t++) {
      int s = t * 256 + tid;
      int d = s >> 3, c0 = (s & 7) * 8;
      *(uint4*)&Vs[d * 72 + c0] =
          *(const uint4*)(vtp + (size_t)d * 4096 + b * 1024 + kt * 64 + c0);
    }
    __syncthreads();

    v4f s_acc[4];
#pragma unroll
    for (int blk = 0; blk < 4; blk++) {
      s_acc[blk] = vzero;
#pragma unroll
      for (int c = 0; c < 4; c++) {
        v8s bk = *(const v8s*)&Ks[(blk * 16 + cl) * 136 + c * 32 + rq * 8];
        s_acc[blk] = __builtin_amdgcn_mfma_f32_16x16x32_bf16(aq[c], bk, s_acc[blk], 0, 0, 0);
      }
    }
#pragma unroll
    for (int blk = 0; blk < 4; blk++)
#pragma unroll
      for (int i = 0; i < 4; i++) {
        float sv = s_acc[blk][i] * 0.088388347648318447f;
        if (kt == qb && (blk * 16 + cl) > (wave * 16 + rq * 4 + i)) sv = -1e30f;
        s_acc[blk][i] = sv;
      }
    float al[4];
#pragma unroll
    for (int i = 0; i < 4; i++) {
      float mx = fmaxf(fmaxf(s_acc[0][i], s_acc[1][i]), fmaxf(s_acc[2][i], s_acc[3][i]));
      mx = fmaxf(mx, __shfl_xor(mx, 1, 64));
      mx = fmaxf(mx, __shfl_xor(mx, 2, 64));
      mx = fmaxf(mx, __shfl_xor(mx, 4, 64));
      mx = fmaxf(mx, __shfl_xor(mx, 8, 64));
      const float mn = fmaxf(m_i[i], mx);
      al[i] = __expf(m_i[i] - mn);
      m_i[i] = mn;
      float ps = 0.f;
#pragma unroll
      for (int blk = 0; blk < 4; blk++) {
        float p = __expf(s_acc[blk][i] - mn);
        s_acc[blk][i] = p;
        ps += p;
      }
      ps += __shfl_xor(ps, 1, 64);
      ps += __shfl_xor(ps, 2, 64);
      ps += __shfl_xor(ps, 4, 64);
      ps += __shfl_xor(ps, 8, 64);
      l_i[i] = l_i[i] * al[i] + ps;
    }
#pragma unroll
    for (int c = 0; c < 8; c++)
#pragma unroll
      for (int i = 0; i < 4; i++) oacc[c][i] *= al[i];
    bf16* ps = Ps[wave];
#pragma unroll
    for (int blk = 0; blk < 4; blk++)
#pragma unroll
      for (int i = 0; i < 4; i++)
        *((unsigned short*)ps + (rq * 4 + i) * 72 + blk * 16 + cl) = f2b_bits(s_acc[blk][i]);
    v8s pa[2];
#pragma unroll
    for (int c = 0; c < 2; c++)
      pa[c] = *(const v8s*)&ps[cl * 72 + c * 32 + rq * 8];
#pragma unroll
    for (int c = 0; c < 8; c++)
#pragma unroll
      for (int ch = 0; ch < 2; ch++) {
        v8s bv = *(const v8s*)&Vs[(c * 16 + cl) * 72 + ch * 32 + rq * 8];
        oacc[c] = __builtin_amdgcn_mfma_f32_16x16x32_bf16(pa[ch], bv, oacc[c], 0, 0, 0);
      }
  }
#pragma unroll
  for (int c = 0; c < 8; c++) {
    const int d = c * 16 + cl;
#pragma unroll
    for (int i = 0; i < 4; i++) {
      const int t = qb * 64 + wave * 16 + rq * 4 + i;
      float* dst = z + ((size_t)(b * 1024 + t)) * 3584 + n * 896 + slot * 128 + d;
      *dst += oacc[c][i] / l_i[i];
    }
  }
}

// ---------------------------------------------------------------------------
extern "C" void kernel_launch(void* const* d_in, const int* in_sizes, int n_in,
                              void* d_out, int out_size, void* d_ws, size_t ws_size,
                              hipStream_t stream)
{
  const float* x        = (const float*)d_in[0];
  const int*   tptr     = (const int*)d_in[1];
  const float* enc_base = (const float*)d_in[2];
  const float* enc_A    = (const float*)d_in[3];
  const float* enc_B    = (const float*)d_in[4];
  const float* beta_p   = (const float*)d_in[5];
  const float* lnm_g    = (const float*)d_in[6];
  const float* lnm_b    = (const float*)d_in[7];
  const float* w1       = (const float*)d_in[8];
  const float* b1       = (const float*)d_in[9];
  const float* w2       = (const float*)d_in[10];
  const float* b2       = (const float*)d_in[11];
  const float* lna_g    = (const float*)d_in[12];
  const float* lna_b    = (const float*)d_in[13];
  const float* Wq       = (const float*)d_in[14];
  const float* Wk       = (const float*)d_in[15];
  const float* Wv       = (const float*)d_in[16];
  const float* dln_g    = (const float*)d_in[17];
  const float* dln_b    = (const float*)d_in[18];
  const float* down_w   = (const float*)d_in[19];
  const float* up_w     = (const float*)d_in[20];

  const bool big = (ws_size >= (size_t)228458496);
  char* ws = (char*)d_ws;
  float* z = (float*)ws;
  char* ra = ws + (size_t)58720256;           // regionA (>=37.7MB both paths)
  bf16 *act, *qkv, *bufb, *w1b, *w2b, *encBt, *Wt;
  if (big) {
    act   = (bf16*)ra;
    qkv   = (bf16*)ra;
    bufb  = (bf16*)(ws + (size_t)176160768);
    w1b   = (bf16*)(ws + (size_t)205520896);
    w2b   = (bf16*)(ws + (size_t)211943424);
    encBt = (bf16*)(ws + (size_t)218365952);
    Wt    = (bf16*)(ws + (size_t)220200960);
  } else {
    act   = (bf16*)ra;
    qkv   = (bf16*)ra;
    bufb  = (bf16*)(ws + (size_t)96468992);
    w1b   = (bf16*)(ws + (size_t)125829120);
    w2b   = (bf16*)(ws + (size_t)132251648);
    encBt = (bf16*)(ws + (size_t)138674176);
    Wt    = (bf16*)(ws + (size_t)140509184);
  }
  bf16* vtb = qkv + (size_t)24 * 4096 * 128;      // V^T lives in the V slot
  // encoder-phase scratch in regionA (dead before mixer writes act):
  bf16* xb    = (bf16*)ra;                        // 4096x1024 bf16 (8.4MB)
  bf16* encAt = (bf16*)(ra + (size_t)8912896);    // 1024x256 (0.5MB)
  bf16* Wz    = (bf16*)(ra + (size_t)9437184);    // 3584x1024 (7.3MB)
  // decoder-phase scratch in regionA (qkv dead after attention):
  bf16* dwT   = (bf16*)ra;                        // 3584x256 (1.8MB)
  bf16* Wdec  = (bf16*)(ra + (size_t)2097152);    // 1024x3584 (7.3MB)

  dim3 blk(256);
  hipMemsetAsync(d_out, 0, (size_t)4096 * 1024 * 4, stream);

  // --- weight conversion / precompute ---
  cvt_kernel<<<1568, blk, 0, stream>>>(w1, w1b, 3211264);
  cvt_kernel<<<1568, blk, 0, stream>>>(w2, w2b, 3211264);
  cvt_kernel<<<2048, blk, 0, stream>>>(x, xb, 4194304);
  cvt_t_kernel<<<dim3(112, 8, 1), blk, 0, stream>>>(enc_B, encBt, 256, 3584);
  cvt_t_kernel<<<dim3(32, 8, 1), blk, 0, stream>>>(enc_A, encAt, 256, 1024);
  cvt_t_kernel<<<dim3(4, 28, 12), blk, 0, stream>>>(Wq, Wt,                      896, 128);
  cvt_t_kernel<<<dim3(4, 28, 12), blk, 0, stream>>>(Wk, Wt + (size_t)12*128*896, 896, 128);
  cvt_t_kernel<<<dim3(4, 28, 12), blk, 0, stream>>>(Wv, Wt + (size_t)24*128*896, 896, 128);
  // Wz[nd,k] = enc_base[nd%896,k] + beta * sum_r encB[r,nd]*encA[r,k]
  mfma_gemm<bf16, bf16, EPI_WZ><<<dim3(8, 28), blk, 0, stream>>>(
      encBt, 256, encAt, 256, Wz, 1024, enc_base, beta_p, 256);

  // encoder: z = xb @ Wz^T   (4096x3584, K=1024)
  mfma_gemm<bf16, bf16, EPI_F32><<<dim3(28, 32), blk, 0, stream>>>(
      xb, 1024, Wz, 1024, z, 3584, nullptr, nullptr, 1024);

  // zm = LN(z) over 896
  ln_kernel<<<dim3(16384), blk, 0, stream>>>(z, lnm_g, lnm_b, bufb, 896);

  // mixer
  if (big) {
    mfma_gemm_sw<bf16, bf16, EPI_GELU><<<dim3(3584), blk, 0, stream>>>(bufb, 896, w1b, 896, act, 3584, b1, nullptr, 896);
    mfma_gemm_sk_sw<bf16, bf16><<<dim3(1792), blk, 0, stream>>>(act, 3584, w2b, 3584, z, 896, b2, 1792);
  } else {
    for (int c = 0; c < 4; c++) {
      mfma_gemm_sw<bf16, bf16, EPI_GELU><<<dim3(896), blk, 0, stream>>>(
          bufb, 896, w1b + (size_t)c * 896 * 896, 896, act, 896, b1 + c * 896, nullptr, 896);
      if (c == 0)
        mfma_gemm_sw<bf16, bf16, EPI_RESID><<<dim3(896), blk, 0, stream>>>(
            act, 896, w2b + (size_t)c * 896, 3584, z, 896, b2, nullptr, 896);
      else
        mfma_gemm_sw<bf16, bf16, EPI_RESID0><<<dim3(896), blk, 0, stream>>>(
            act, 896, w2b + (size_t)c * 896, 3584, z, 896, nullptr, nullptr, 896);
    }
  }

  // hin = LN(z) over 896
  ln_kernel<<<dim3(16384), blk, 0, stream>>>(z, lna_g, lna_b, bufb, 896);
  // q,k projections ([t][d]) and v projection (direct V^T)
  qkv_mfma<<<dim3(1, 32, 24), blk, 0, stream>>>(bufb, Wt, qkv, tptr);
  qkv_v_mfma<<<dim3(1, 32, 12), blk, 0, stream>>>(bufb, Wt, vtb, tptr);
  // flash attention, adds into z slots
  attn_mfma<<<dim3(16, 48), blk, 0, stream>>>(qkv, vtb, z, tptr);

  // decoder precompute (qkv dead now): Wdec[i,c] = sum_r up_w[i,r]*down_w[r,c]
  cvt_t_kernel<<<dim3(112, 8, 1), blk, 0, stream>>>(down_w, dwT, 256, 3584);
  mfma_gemm<float, bf16, EPI_BF16><<<dim3(28, 8), blk, 0, stream>>>(
      up_w, 256, dwT, 256, Wdec, 3584, nullptr, nullptr, 256);

  // c = LN(z) over 3584
  ln_kernel<<<dim3(4096), blk, 0, stream>>>(z, dln_g, dln_b, bufb, 3584);
  // y = c @ Wdec^T  (4096x1024, K=3584, split-K=4, atomic into zeroed d_out)
  mfma_gemm_sk<bf16, bf16><<<dim3(8, 32, 4), blk, 0, stream>>>(
      bufb, 3584, Wdec, 3584, (float*)d_out, 1024, nullptr, 896);
}

// Round 9
// 896.414 us; speedup vs baseline: 1.1417x; 1.0971x over previous
//
#include <hip/hip_runtime.h>
#include <hip/hip_bf16.h>
#include <math.h>

typedef __hip_bfloat16 bf16;
typedef __attribute__((ext_vector_type(8))) short v8s;
typedef __attribute__((ext_vector_type(4))) float v4f;

#define EPI_F32    0
#define EPI_BF16   1
#define EPI_GELU   2
#define EPI_RESID  3
#define EPI_RESID0 4
#define EPI_WZ     5   // out_bf16 = beta*acc + enc_base[(r%896)*1024+col]
#define EPI_ATOM   6   // atomicAdd(C_f32, acc + (bias?bias[col]:0))
#define EPI_VT     7   // transposed bf16 store: C[(col)*4096 + r]

// ---------- bf16 helpers ----------
__device__ __forceinline__ float bf_lo(unsigned int w) { return __uint_as_float(w << 16); }
__device__ __forceinline__ float bf_hi(unsigned int w) { return __uint_as_float(w & 0xffff0000u); }
__device__ __forceinline__ unsigned short f2b_bits(float f) {
  unsigned int u = __float_as_uint(f);
  unsigned int r = (u + 0x7fffu + ((u >> 16) & 1u)) >> 16;   // RTNE
  return (unsigned short)r;
}
__device__ __forceinline__ void unpack8(uint4 u, float* f) {
  unsigned int w0 = u.x, w1 = u.y, w2 = u.z, w3 = u.w;
  f[0] = bf_lo(w0); f[1] = bf_hi(w0);
  f[2] = bf_lo(w1); f[3] = bf_hi(w1);
  f[4] = bf_lo(w2); f[5] = bf_hi(w2);
  f[6] = bf_lo(w3); f[7] = bf_hi(w3);
}
__device__ __forceinline__ void load8(const float* p, float* f) {
  float4 a = ((const float4*)p)[0];
  float4 b = ((const float4*)p)[1];
  f[0] = a.x; f[1] = a.y; f[2] = a.z; f[3] = a.w;
  f[4] = b.x; f[5] = b.y; f[6] = b.z; f[7] = b.w;
}
__device__ __forceinline__ void gl_lds16(const void* g, void* l) {
  __builtin_amdgcn_global_load_lds(
      (__attribute__((address_space(1))) void*)g,
      (__attribute__((address_space(3))) void*)l, 16, 0, 0);
}

// ---------- conversion kernels ----------
__global__ __launch_bounds__(256) void cvt_kernel(const float* __restrict__ src,
                                                  bf16* __restrict__ dst, int n)
{
  int i = (blockIdx.x * 256 + threadIdx.x) * 8;
  if (i >= n) return;
  float f[8]; load8(src + i, f);
  unsigned short us[8];
#pragma unroll
  for (int j = 0; j < 8; j++) us[j] = f2b_bits(f[j]);
  *(uint4*)((unsigned short*)dst + i) = *(uint4*)us;
}

__global__ __launch_bounds__(256) void cvt_t_kernel(const float* __restrict__ src,
                                                    bf16* __restrict__ dst, int R, int C)
{
  __shared__ float tile[32][33];
  const int c0 = blockIdx.x * 32, r0 = blockIdx.y * 32;
  const size_t bo = (size_t)blockIdx.z * R * C;
  const int tx = threadIdx.x & 31, ty = threadIdx.x >> 5;
#pragma unroll
  for (int i = 0; i < 4; i++) {
    int r = ty * 4 + i;
    tile[r][tx] = src[bo + (size_t)(r0 + r) * C + c0 + tx];
  }
  __syncthreads();
#pragma unroll
  for (int i = 0; i < 4; i++) {
    int r = ty * 4 + i;
    *((unsigned short*)dst + bo + (size_t)(c0 + r) * R + r0 + tx) = f2b_bits(tile[tx][r]);
  }
}

// ---------- MFMA GEMM core, async-staged, BK=64 (2x proven stride-32 tiles) ----------
__device__ __forceinline__ void stage_async(const bf16* __restrict__ src, int ld, int r0, int k0,
                                            bf16* lds, int wave, int lane)
{
#pragma unroll
  for (int t = 0; t < 2; t++) {
    int seg = wave * 2 + t;
    const bf16* g = src + (size_t)(r0 + seg * 16 + (lane >> 2)) * ld + k0 + (lane & 3) * 8;
    gl_lds16(g, lds + seg * 512);
  }
}
__device__ __forceinline__ void stage_sync(const float* __restrict__ src, int ld, int r0, int k0,
                                           bf16* lds, int tid)
{
#pragma unroll
  for (int t = 0; t < 2; t++) {
    int s = t * 256 + tid;
    int m = s >> 2, c = s & 3;
    float f[8]; load8(src + (size_t)(r0 + m) * ld + k0 + c * 8, f);
    unsigned short us[8];
#pragma unroll
    for (int j = 0; j < 8; j++) us[j] = f2b_bits(f[j]);
    *(uint4*)&lds[m * 32 + c * 8] = *(uint4*)us;
  }
}
__device__ __forceinline__ void stage_tile(const bf16* __restrict__ src, int ld, int r0, int k0,
                                           bf16* lds, int tid, int wave, int lane)
{ stage_async(src, ld, r0, k0, lds, wave, lane); }
__device__ __forceinline__ void stage_tile(const float* __restrict__ src, int ld, int r0, int k0,
                                           bf16* lds, int tid, int wave, int lane)
{ stage_sync(src, ld, r0, k0, lds, tid); }

template<typename TA, typename TB, int EPI>
__device__ void mfma_core(const TA* __restrict__ A, int lda,
                          const TB* __restrict__ B, int ldb,
                          void* __restrict__ C, int ldc,
                          const float* __restrict__ bias,
                          const float* __restrict__ beta_p,
                          int m0, int n0, int K)
{
  __shared__ bf16 As[2][128 * 32];
  __shared__ bf16 Bs[2][128 * 32];
  const int tid = threadIdx.x;
  const int lane = tid & 63, wave = tid >> 6;
  const int mw = (wave & 1) * 64, nw = (wave >> 1) * 64;
  const int row = lane & 15, kc = lane >> 4;

  v4f acc[4][4];
  const v4f vzero = {0.f, 0.f, 0.f, 0.f};
#pragma unroll
  for (int i = 0; i < 4; i++)
#pragma unroll
    for (int j = 0; j < 4; j++) acc[i][j] = vzero;

  for (int k0 = 0; k0 < K; k0 += 64) {
    stage_tile(A, lda, m0, k0,      As[0], tid, wave, lane);
    stage_tile(A, lda, m0, k0 + 32, As[1], tid, wave, lane);
    stage_tile(B, ldb, n0, k0,      Bs[0], tid, wave, lane);
    stage_tile(B, ldb, n0, k0 + 32, Bs[1], tid, wave, lane);
    __syncthreads();   // drains vmcnt (async LDS stores) + lgkm
#pragma unroll
    for (int h = 0; h < 2; h++) {
      v8s af[4], bfr[4];
#pragma unroll
      for (int i = 0; i < 4; i++)
        af[i] = *(const v8s*)&As[h][(mw + i * 16 + row) * 32 + kc * 8];
#pragma unroll
      for (int j = 0; j < 4; j++)
        bfr[j] = *(const v8s*)&Bs[h][(nw + j * 16 + row) * 32 + kc * 8];
#pragma unroll
      for (int i = 0; i < 4; i++)
#pragma unroll
        for (int j = 0; j < 4; j++)
          acc[i][j] = __builtin_amdgcn_mfma_f32_16x16x32_bf16(af[i], bfr[j], acc[i][j], 0, 0, 0);
    }
    __syncthreads();
  }

  const int cl = lane & 15, rq = lane >> 4;
  if (EPI == EPI_VT) {
#pragma unroll
    for (int mi = 0; mi < 4; mi++) {
#pragma unroll
      for (int nj = 0; nj < 4; nj++) {
        const int col = n0 + nw + nj * 16 + cl;
        const int rb = m0 + mw + mi * 16 + rq * 4;
        unsigned short us[4];
#pragma unroll
        for (int i = 0; i < 4; i++) us[i] = f2b_bits(acc[mi][nj][i]);
        *(ushort2*)((unsigned short*)C + (size_t)col * 4096 + rb) = *(ushort2*)us;
        *(ushort2*)((unsigned short*)C + (size_t)col * 4096 + rb + 2) = *(ushort2*)(us + 2);
      }
    }
    return;
  }
  const float beta = (EPI == EPI_WZ) ? beta_p[0] : 0.f;
#pragma unroll
  for (int mi = 0; mi < 4; mi++) {
#pragma unroll
    for (int nj = 0; nj < 4; nj++) {
      const int col = n0 + nw + nj * 16 + cl;
#pragma unroll
      for (int i = 0; i < 4; i++) {
        const int r = m0 + mw + mi * 16 + rq * 4 + i;
        float v = acc[mi][nj][i];
        if (EPI == EPI_F32) {
          ((float*)C)[(size_t)r * ldc + col] = v;
        } else if (EPI == EPI_BF16) {
          ((unsigned short*)C)[(size_t)r * ldc + col] = f2b_bits(v);
        } else if (EPI == EPI_GELU) {
          v += bias[col];
          v = 0.5f * v * (1.f + erff(v * 0.70710678118654752f));
          ((unsigned short*)C)[(size_t)r * ldc + col] = f2b_bits(v);
        } else if (EPI == EPI_RESID) {
          float* Z = (float*)C;
          size_t idx = (size_t)r * ldc + col;
          Z[idx] = Z[idx] + v + bias[col];
        } else if (EPI == EPI_RESID0) {
          float* Z = (float*)C;
          size_t idx = (size_t)r * ldc + col;
          Z[idx] = Z[idx] + v;
        } else if (EPI == EPI_WZ) {
          float o = beta * v + bias[(size_t)(r % 896) * 1024 + col];
          ((unsigned short*)C)[(size_t)r * ldc + col] = f2b_bits(o);
        } else if (EPI == EPI_ATOM) {
          float add = v + (bias ? bias[col] : 0.f);
          atomicAdd(&((float*)C)[(size_t)r * ldc + col], add);
        }
      }
    }
  }
}

template<typename TA, typename TB, int EPI>
__global__ __launch_bounds__(256) void mfma_gemm(const TA* __restrict__ A, int lda,
                                                 const TB* __restrict__ B, int ldb,
                                                 void* __restrict__ C, int ldc,
                                                 const float* __restrict__ bias,
                                                 const float* __restrict__ beta_p, int K)
{
  mfma_core<TA, TB, EPI>(A, lda, B, ldb, C, ldc, bias, beta_p,
                         blockIdx.y * 128, blockIdx.x * 128, K);
}

// XCD-swizzled variant for M=16384 (128 M-blocks)
template<typename TA, typename TB, int EPI>
__global__ __launch_bounds__(256) void mfma_gemm_sw(const TA* __restrict__ A, int lda,
                                                    const TB* __restrict__ B, int ldb,
                                                    void* __restrict__ C, int ldc,
                                                    const float* __restrict__ bias,
                                                    const float* __restrict__ beta_p, int K)
{
  const int lin = blockIdx.x;
  const int m0 = ((((lin & 7) << 4) | ((lin >> 3) & 15))) * 128;
  const int n0 = (lin >> 7) * 128;
  mfma_core<TA, TB, EPI>(A, lda, B, ldb, C, ldc, bias, beta_p, m0, n0, K);
}

// plain split-K atomic variant: grid (Nb, Mb, SK)
template<typename TA, typename TB>
__global__ __launch_bounds__(256) void mfma_gemm_sk(const TA* __restrict__ A, int lda,
                                                    const TB* __restrict__ B, int ldb,
                                                    float* __restrict__ C, int ldc,
                                                    const float* __restrict__ bias, int Kc)
{
  const int kofs = blockIdx.z * Kc;
  mfma_core<TA, TB, EPI_ATOM>(A + kofs, lda, B + kofs, ldb, C, ldc,
                              (blockIdx.z == 0) ? bias : nullptr, nullptr,
                              blockIdx.y * 128, blockIdx.x * 128, Kc);
}

// ---------- batched QK projection (types 0,1) ----------
__global__ __launch_bounds__(256) void qkv_mfma(const bf16* __restrict__ hin,
                                                const bf16* __restrict__ Wt,
                                                bf16* __restrict__ qkv,
                                                const int* __restrict__ tptr)
{
  const int zb = blockIdx.z;
  const int type = zb / 12, rem = zb % 12, n = rem / 3, kh = rem % 3;
  const int phase = ((tptr[0] % 4) + 4) % 4;
  const int hid = (kh == 0) ? n
                : (kh == 1) ? 4 + (n + 2 * (phase & 1)) % 4
                            : 8 + (n + phase) % 4;
  const bf16* B = Wt + ((size_t)type * 12 + hid) * 128 * 896;
  bf16* out = qkv + ((size_t)type * 12 + n * 3 + kh) * 4096 * 128;
  mfma_core<bf16, bf16, EPI_BF16>(hin + n * 896, 3584, B, 896, out, 128,
                                  nullptr, nullptr, blockIdx.y * 128, 0, 896);
}

// ---------- V projection, writes V^T [head][128][4096] directly ----------
__global__ __launch_bounds__(256) void qkv_v_mfma(const bf16* __restrict__ hin,
                                                  const bf16* __restrict__ Wt,
                                                  bf16* __restrict__ vt,
                                                  const int* __restrict__ tptr)
{
  const int rem = blockIdx.z, n = rem / 3, kh = rem % 3;
  const int phase = ((tptr[0] % 4) + 4) % 4;
  const int hid = (kh == 0) ? n
                : (kh == 1) ? 4 + (n + 2 * (phase & 1)) % 4
                            : 8 + (n + phase) % 4;
  const bf16* B = Wt + ((size_t)2 * 12 + hid) * 128 * 896;
  bf16* out = vt + (size_t)(n * 3 + kh) * 128 * 4096;
  mfma_core<bf16, bf16, EPI_VT>(hin + n * 896, 3584, B, 896, out, 0,
                                nullptr, nullptr, blockIdx.y * 128, 0, 896);
}

// ---------- LayerNorm ----------
__global__ __launch_bounds__(256) void ln_kernel(const float* __restrict__ in,
                                                 const float* __restrict__ g,
                                                 const float* __restrict__ bsh,
                                                 bf16* __restrict__ out, int D)
{
  __shared__ float row[3584];
  __shared__ float red[256];
  const int tid = threadIdx.x;
  const size_t base = (size_t)blockIdx.x * D;
  float s = 0.f;
  for (int i = tid; i < D; i += 256) { float v = in[base + i]; row[i] = v; s += v; }
  red[tid] = s; __syncthreads();
  for (int o = 128; o > 0; o >>= 1) { if (tid < o) red[tid] += red[tid + o]; __syncthreads(); }
  const float mean = red[0] / (float)D;
  __syncthreads();
  s = 0.f;
  for (int i = tid; i < D; i += 256) { float d = row[i] - mean; s += d * d; }
  red[tid] = s; __syncthreads();
  for (int o = 128; o > 0; o >>= 1) { if (tid < o) red[tid] += red[tid + o]; __syncthreads(); }
  const float inv = rsqrtf(red[0] / (float)D + 1e-5f);
  for (int i = tid; i < D; i += 256) {
    float v = (row[i] - mean) * inv * g[i] + bsh[i];
    *((unsigned short*)out + base + i) = f2b_bits(v);
  }
}

// ---------- MFMA flash attention ----------
__global__ __launch_bounds__(256) void attn_mfma(const bf16* __restrict__ qkv,
                                                 const bf16* __restrict__ vt,
                                                 float* __restrict__ z,
                                                 const int* __restrict__ tptr)
{
  __shared__ bf16 Ks[64 * 136];
  __shared__ bf16 Vs[128 * 72];
  __shared__ bf16 Ps[4][16 * 72];
  const int tid = threadIdx.x;
  const int lane = tid & 63, wave = tid >> 6;
  const int cl = lane & 15, rq = lane >> 4;
  const int qb = 15 - blockIdx.x;
  const int bnk = blockIdx.y;
  const int b = bnk / 12, rem = bnk % 12, n = rem / 3, kh = rem % 3;
  const int phase = ((tptr[0] % 4) + 4) % 4;
  const int slot = (kh == 0) ? 0 : (kh == 1) ? 1 + (phase & 1) : 3 + phase;
  const int head = n * 3 + kh;
  const size_t HS = (size_t)12 * 4096 * 128;
  const bf16* qp = qkv + ((size_t)head * 4096 + b * 1024) * 128;
  const bf16* kp = qkv + HS + ((size_t)head * 4096 + b * 1024) * 128;
  const bf16* vtp = vt + (size_t)head * 128 * 4096;

  v8s aq[4];
  {
    const bf16* qrow = qp + (size_t)(qb * 64 + wave * 16 + cl) * 128 + rq * 8;
#pragma unroll
    for (int c = 0; c < 4; c++) aq[c] = *(const v8s*)(qrow + c * 32);
  }
  v4f oacc[8];
  const v4f vzero = {0.f, 0.f, 0.f, 0.f};
#pragma unroll
  for (int c = 0; c < 8; c++) oacc[c] = vzero;
  float m_i[4] = {-1e30f, -1e30f, -1e30f, -1e30f};
  float l_i[4] = {0.f, 0.f, 0.f, 0.f};

  for (int kt = 0; kt <= qb; kt++) {
    __syncthreads();
#pragma unroll
    for (int t = 0; t < 4; t++) {
      int s = t * 256 + tid;
      int r = s >> 4, c0 = (s & 15) * 8;
      *(uint4*)&Ks[r * 136 + c0] = *(const uint4*)(kp + (size_t)(kt * 64 + r) * 128 + c0);
    }
#pragma unroll
    for (int t = 0; t < 4; t++) {
      int s = t * 256 + tid;
      int d = s >> 3, c0 = (s & 7) * 8;
      *(uint4*)&Vs[d * 72 + c0] =
          *(const uint4*)(vtp + (size_t)d * 4096 + b * 1024 + kt * 64 + c0);
    }
    __syncthreads();

    v4f s_acc[4];
#pragma unroll
    for (int blk = 0; blk < 4; blk++) {
      s_acc[blk] = vzero;
#pragma unroll
      for (int c = 0; c < 4; c++) {
        v8s bk = *(const v8s*)&Ks[(blk * 16 + cl) * 136 + c * 32 + rq * 8];
        s_acc[blk] = __builtin_amdgcn_mfma_f32_16x16x32_bf16(aq[c], bk, s_acc[blk], 0, 0, 0);
      }
    }
#pragma unroll
    for (int blk = 0; blk < 4; blk++)
#pragma unroll
      for (int i = 0; i < 4; i++) {
        float sv = s_acc[blk][i] * 0.088388347648318447f;
        if (kt == qb && (blk * 16 + cl) > (wave * 16 + rq * 4 + i)) sv = -1e30f;
        s_acc[blk][i] = sv;
      }
    float al[4];
#pragma unroll
    for (int i = 0; i < 4; i++) {
      float mx = fmaxf(fmaxf(s_acc[0][i], s_acc[1][i]), fmaxf(s_acc[2][i], s_acc[3][i]));
      mx = fmaxf(mx, __shfl_xor(mx, 1, 64));
      mx = fmaxf(mx, __shfl_xor(mx, 2, 64));
      mx = fmaxf(mx, __shfl_xor(mx, 4, 64));
      mx = fmaxf(mx, __shfl_xor(mx, 8, 64));
      const float mn = fmaxf(m_i[i], mx);
      al[i] = __expf(m_i[i] - mn);
      m_i[i] = mn;
      float ps = 0.f;
#pragma unroll
      for (int blk = 0; blk < 4; blk++) {
        float p = __expf(s_acc[blk][i] - mn);
        s_acc[blk][i] = p;
        ps += p;
      }
      ps += __shfl_xor(ps, 1, 64);
      ps += __shfl_xor(ps, 2, 64);
      ps += __shfl_xor(ps, 4, 64);
      ps += __shfl_xor(ps, 8, 64);
      l_i[i] = l_i[i] * al[i] + ps;
    }
#pragma unroll
    for (int c = 0; c < 8; c++)
#pragma unroll
      for (int i = 0; i < 4; i++) oacc[c][i] *= al[i];
    bf16* ps = Ps[wave];
#pragma unroll
    for (int blk = 0; blk < 4; blk++)
#pragma unroll
      for (int i = 0; i < 4; i++)
        *((unsigned short*)ps + (rq * 4 + i) * 72 + blk * 16 + cl) = f2b_bits(s_acc[blk][i]);
    v8s pa[2];
#pragma unroll
    for (int c = 0; c < 2; c++)
      pa[c] = *(const v8s*)&ps[cl * 72 + c * 32 + rq * 8];
#pragma unroll
    for (int c = 0; c < 8; c++)
#pragma unroll
      for (int ch = 0; ch < 2; ch++) {
        v8s bv = *(const v8s*)&Vs[(c * 16 + cl) * 72 + ch * 32 + rq * 8];
        oacc[c] = __builtin_amdgcn_mfma_f32_16x16x32_bf16(pa[ch], bv, oacc[c], 0, 0, 0);
      }
  }
#pragma unroll
  for (int c = 0; c < 8; c++) {
    const int d = c * 16 + cl;
#pragma unroll
    for (int i = 0; i < 4; i++) {
      const int t = qb * 64 + wave * 16 + rq * 4 + i;
      float* dst = z + ((size_t)(b * 1024 + t)) * 3584 + n * 896 + slot * 128 + d;
      *dst += oacc[c][i] / l_i[i];
    }
  }
}

// ---------------------------------------------------------------------------
extern "C" void kernel_launch(void* const* d_in, const int* in_sizes, int n_in,
                              void* d_out, int out_size, void* d_ws, size_t ws_size,
                              hipStream_t stream)
{
  const float* x        = (const float*)d_in[0];
  const int*   tptr     = (const int*)d_in[1];
  const float* enc_base = (const float*)d_in[2];
  const float* enc_A    = (const float*)d_in[3];
  const float* enc_B    = (const float*)d_in[4];
  const float* beta_p   = (const float*)d_in[5];
  const float* lnm_g    = (const float*)d_in[6];
  const float* lnm_b    = (const float*)d_in[7];
  const float* w1       = (const float*)d_in[8];
  const float* b1       = (const float*)d_in[9];
  const float* w2       = (const float*)d_in[10];
  const float* b2       = (const float*)d_in[11];
  const float* lna_g    = (const float*)d_in[12];
  const float* lna_b    = (const float*)d_in[13];
  const float* Wq       = (const float*)d_in[14];
  const float* Wk       = (const float*)d_in[15];
  const float* Wv       = (const float*)d_in[16];
  const float* dln_g    = (const float*)d_in[17];
  const float* dln_b    = (const float*)d_in[18];
  const float* down_w   = (const float*)d_in[19];
  const float* up_w     = (const float*)d_in[20];

  const bool big = (ws_size >= (size_t)228458496);
  char* ws = (char*)d_ws;
  float* z = (float*)ws;
  char* ra = ws + (size_t)58720256;           // regionA (>=37.7MB both paths)
  bf16 *act, *qkv, *bufb, *w1b, *w2b, *encBt, *Wt;
  if (big) {
    act   = (bf16*)ra;
    qkv   = (bf16*)ra;
    bufb  = (bf16*)(ws + (size_t)176160768);
    w1b   = (bf16*)(ws + (size_t)205520896);
    w2b   = (bf16*)(ws + (size_t)211943424);
    encBt = (bf16*)(ws + (size_t)218365952);
    Wt    = (bf16*)(ws + (size_t)220200960);
  } else {
    act   = (bf16*)ra;
    qkv   = (bf16*)ra;
    bufb  = (bf16*)(ws + (size_t)96468992);
    w1b   = (bf16*)(ws + (size_t)125829120);
    w2b   = (bf16*)(ws + (size_t)132251648);
    encBt = (bf16*)(ws + (size_t)138674176);
    Wt    = (bf16*)(ws + (size_t)140509184);
  }
  bf16* vtb = qkv + (size_t)24 * 4096 * 128;      // V^T lives in the V slot
  bf16* xb    = (bf16*)ra;                        // 4096x1024 bf16 (8.4MB)
  bf16* encAt = (bf16*)(ra + (size_t)8912896);    // 1024x256 (0.5MB)
  bf16* Wz    = (bf16*)(ra + (size_t)9437184);    // 3584x1024 (7.3MB)
  bf16* dwT   = (bf16*)ra;                        // 3584x256 (1.8MB)
  bf16* Wdec  = (bf16*)(ra + (size_t)2097152);    // 1024x3584 (7.3MB)

  dim3 blk(256);
  hipMemsetAsync(d_out, 0, (size_t)4096 * 1024 * 4, stream);

  // --- weight conversion / precompute ---
  cvt_kernel<<<1568, blk, 0, stream>>>(w1, w1b, 3211264);
  cvt_kernel<<<1568, blk, 0, stream>>>(w2, w2b, 3211264);
  cvt_kernel<<<2048, blk, 0, stream>>>(x, xb, 4194304);
  cvt_t_kernel<<<dim3(112, 8, 1), blk, 0, stream>>>(enc_B, encBt, 256, 3584);
  cvt_t_kernel<<<dim3(32, 8, 1), blk, 0, stream>>>(enc_A, encAt, 256, 1024);
  cvt_t_kernel<<<dim3(4, 28, 12), blk, 0, stream>>>(Wq, Wt,                      896, 128);
  cvt_t_kernel<<<dim3(4, 28, 12), blk, 0, stream>>>(Wk, Wt + (size_t)12*128*896, 896, 128);
  cvt_t_kernel<<<dim3(4, 28, 12), blk, 0, stream>>>(Wv, Wt + (size_t)24*128*896, 896, 128);
  // Wz[nd,k] = enc_base[nd%896,k] + beta * sum_r encB[r,nd]*encA[r,k]
  mfma_gemm<bf16, bf16, EPI_WZ><<<dim3(8, 28), blk, 0, stream>>>(
      encBt, 256, encAt, 256, Wz, 1024, enc_base, beta_p, 256);

  // encoder: z = xb @ Wz^T   (4096x3584, K=1024)
  mfma_gemm<bf16, bf16, EPI_F32><<<dim3(28, 32), blk, 0, stream>>>(
      xb, 1024, Wz, 1024, z, 3584, nullptr, nullptr, 1024);

  // zm = LN(z) over 896
  ln_kernel<<<dim3(16384), blk, 0, stream>>>(z, lnm_g, lnm_b, bufb, 896);

  // mixer
  if (big) {
    mfma_gemm_sw<bf16, bf16, EPI_GELU><<<dim3(3584), blk, 0, stream>>>(bufb, 896, w1b, 896, act, 3584, b1, nullptr, 896);
    mfma_gemm_sw<bf16, bf16, EPI_RESID><<<dim3(896), blk, 0, stream>>>(act, 3584, w2b, 3584, z, 896, b2, nullptr, 3584);
  } else {
    for (int c = 0; c < 4; c++) {
      mfma_gemm_sw<bf16, bf16, EPI_GELU><<<dim3(896), blk, 0, stream>>>(
          bufb, 896, w1b + (size_t)c * 896 * 896, 896, act, 896, b1 + c * 896, nullptr, 896);
      if (c == 0)
        mfma_gemm_sw<bf16, bf16, EPI_RESID><<<dim3(896), blk, 0, stream>>>(
            act, 896, w2b + (size_t)c * 896, 3584, z, 896, b2, nullptr, 896);
      else
        mfma_gemm_sw<bf16, bf16, EPI_RESID0><<<dim3(896), blk, 0, stream>>>(
            act, 896, w2b + (size_t)c * 896, 3584, z, 896, nullptr, nullptr, 896);
    }
  }

  // hin = LN(z) over 896
  ln_kernel<<<dim3(16384), blk, 0, stream>>>(z, lna_g, lna_b, bufb, 896);
  // q,k projections ([t][d]) and v projection (direct V^T)
  qkv_mfma<<<dim3(1, 32, 24), blk, 0, stream>>>(bufb, Wt, qkv, tptr);
  qkv_v_mfma<<<dim3(1, 32, 12), blk, 0, stream>>>(bufb, Wt, vtb, tptr);
  // flash attention, adds into z slots
  attn_mfma<<<dim3(16, 48), blk, 0, stream>>>(qkv, vtb, z, tptr);

  // decoder precompute (qkv dead now): Wdec[i,c] = sum_r up_w[i,r]*down_w[r,c]
  cvt_t_kernel<<<dim3(112, 8, 1), blk, 0, stream>>>(down_w, dwT, 256, 3584);
  mfma_gemm<float, bf16, EPI_BF16><<<dim3(28, 8), blk, 0, stream>>>(
      up_w, 256, dwT, 256, Wdec, 3584, nullptr, nullptr, 256);

  // c = LN(z) over 3584
  ln_kernel<<<dim3(4096), blk, 0, stream>>>(z, dln_g, dln_b, bufb, 3584);
  // y = c @ Wdec^T  (4096x1024, K=3584, split-K=4, atomic into zeroed d_out)
  mfma_gemm_sk<bf16, bf16><<<dim3(8, 32, 4), blk, 0, stream>>>(
      bufb, 3584, Wdec, 3584, (float*)d_out, 1024, nullptr, 896);
}